// Round 9
// baseline (244.442 us; speedup 1.0000x reference)
//
#include <hip/hip_runtime.h>

// Problem: B,H,W,D = 64,32,32,64 ; K=1024 ; N = 65536
#define NPTS   65536
#define DDIM   64
#define KCODES 1024
#define QOUT_ELEMS (NPTS * DDIM)

typedef _Float16 half8    __attribute__((ext_vector_type(8)));
typedef float    floatx16 __attribute__((ext_vector_type(16)));
typedef unsigned int uint;

#define AS1 __attribute__((address_space(1)))
#define AS3 __attribute__((address_space(3)))

// ws: ehp [0,128K) chunk-major f16 | elp [128K,256K) | e2 fp32 [256K,260K)
#define WS_EHP   0
#define WS_ELP   (128*1024)
#define WS_E2    (256*1024)

static __device__ __forceinline__ void gl_lds16(const void* g, void* l) {
    __builtin_amdgcn_global_load_lds((const AS1 uint*)g, (AS3 uint*)l, 16, 0, 0);
}

// ---------------------------------------------------------------------------
// Prep: one wave per code. fp16 hi/lo split, CHUNK-MAJOR tiles:
// tile T=k>>5, chunk j=d>>3, code-in-tile c=k&31:
//   byte off = T*4096 + j*512 + c*16 + (d&7)*2
// e2 (||e||^2) stored as plain fp32 (added post-MFMA, exact).
// ---------------------------------------------------------------------------
__global__ void eprep_kernel(const float* __restrict__ emb, char* __restrict__ ws) {
    const int tid = threadIdx.x;
    const int w = tid >> 6, d = tid & 63;
    const int k = blockIdx.x * 4 + w;
    float v = emb[(size_t)k * DDIM + d];
    _Float16 h = (_Float16)v;
    _Float16 l = (_Float16)(v - (float)h);
    size_t off = (size_t)(k >> 5) * 4096 + (size_t)(d >> 3) * 512
               + (size_t)(k & 31) * 16 + (size_t)(d & 7) * 2;
    *(_Float16*)(ws + WS_EHP + off) = h;
    *(_Float16*)(ws + WS_ELP + off) = l;
    float s = v * v;
    #pragma unroll
    for (int m = 1; m < 64; m <<= 1) s += __shfl_xor(s, m, 64);
    if (d == 0) ((float*)(ws + WS_E2))[k] = s;
}

// ---------------------------------------------------------------------------
// Main: grid 1024, block 256 = 4 waves, 64 points per block.
// Round-9 change: OCCUPANCY. Grid was the occupancy binder all along
// (512 blocks = 2 blocks/CU = 2 waves/SIMD; VGPR 104 / LDS 37KB support 4).
// K-SPLIT inside the block: waves {0,1} -> tiles 0..15, waves {2,3} ->
// 16..31, same 64 points; 1024 blocks = exactly 4 blocks/CU = 4 waves/SIMD,
// each SIMD's waves drawn from 4 INDEPENDENT blocks (unsynchronized).
// Pipeline: R6's counted-wait + raw s_barrier + READF-ahead, ring-2 per
// pair (depth-1 prefetch: STAGE(t+1) issued a full COMP before its wait).
// COMP: R6's two 6-deep chains (R8's 4-chain spilled: WRITE_SIZE 125MB of
// scratch at VGPR cap 128 -> keep <=120 arch VGPRs).
// Epilogue: R2's proven half-combine (half-0 codes all smaller -> strict <).
//
// MFMA 32x32x16 f16 layouts (verified, absmax 0):
//   A[m][k]: m=lane&31, k=(lane>>5)*8+j ; B same with n=lane&31 ;
//   C/D: col=lane&31, row=(r&3)+8*(r>>2)+4*(lane>>5)
// ---------------------------------------------------------------------------
#define MFMA(A,B,C) __builtin_amdgcn_mfma_f32_32x32x16_f16(A,B,C,0,0,0)

__global__ __launch_bounds__(256, 4) void vq_kernel(
    const float* __restrict__ z,
    const char* __restrict__ ws_c,
    const float* __restrict__ emb,
    float* __restrict__ out)
{
    const int tid   = threadIdx.x;
    const int lane  = tid & 63;
    const int w     = __builtin_amdgcn_readfirstlane(tid >> 6);
    const int col   = lane & 31;
    const int sel8  = lane >> 5;
    const int pgrp  = blockIdx.x;      // 64 points per block
    const int pair  = w >> 1;          // K-half: 0 -> tiles 0..15, 1 -> 16..31
    const int phalf = w & 1;           // point sub-group AND staging operand
    const int tbase = pair * 16;

    __shared__ char  ebuf[2][2][8192]; // [pair][slot][eh 4KB | el 4KB] = 32KB
    __shared__ float lds_e2[1024];     // 4KB fp32 ||e||^2, all codes
    __shared__ float sbest[2][64];
    __shared__ int   scode[2][64];
    __shared__ int   s_final[64];

    // ---- A fragments: a = -2 z[pt], hi/lo fp16 ----
    const int pt = pgrp * 64 + phalf * 32 + col;
    half8 ah[4], al[4];
    {
        const float* zrow = z + (size_t)pt * DDIM + sel8 * 8;
        #pragma unroll
        for (int ks = 0; ks < 4; ++ks) {
            float4 u0 = *(const float4*)(zrow + ks * 16);
            float4 u1 = *(const float4*)(zrow + ks * 16 + 4);
            float tv[8] = {u0.x, u0.y, u0.z, u0.w, u1.x, u1.y, u1.z, u1.w};
            #pragma unroll
            for (int j = 0; j < 8; ++j) {
                float a = -2.0f * tv[j];
                _Float16 hh = (_Float16)a;
                ah[ks][j] = hh;
                al[ks][j] = (_Float16)(a - (float)hh);
            }
        }
    }
    // drain A-frag vmem so loop vmcnt accounting sees ONLY gl_lds ops
    asm volatile("s_waitcnt vmcnt(0)" ::: "memory");
    __builtin_amdgcn_sched_barrier(0);

    const floatx16 zeroC = {};
    float best[16];
    int   bt[16];
    #pragma unroll
    for (int r = 0; r < 16; ++r) { best[r] = 3.4e38f; bt[r] = 0; }

    // wave (pair,phalf) stages operand phalf (0=eh,1=el) 4KB/tile for ITS pair
    const char* gsrc = ws_c + (phalf ? WS_ELP : WS_EHP) + lane * 16;
    char* lbase = &ebuf[pair][0][0] + phalf * 4096 + lane * 16;

#define STAGE(SLOT, T) do {                                                   \
    const char* _s = gsrc + (size_t)(tbase + (T)) * 4096;                     \
    char* _d = lbase + (SLOT) * 8192;                                         \
    gl_lds16(_s,        _d);                                                  \
    gl_lds16(_s + 1024, _d + 1024);                                           \
    gl_lds16(_s + 2048, _d + 2048);                                           \
    gl_lds16(_s + 3072, _d + 3072);                                           \
} while (0)

    const int myoff = sel8 * 512 + col * 16;   // chunk-major frag base in tile

#define READF(SLOT, T, BH, BL, E2) do {                                       \
    const char* _b = &ebuf[pair][SLOT][0] + myoff;                            \
    _Pragma("unroll")                                                         \
    for (int ks = 0; ks < 4; ++ks) {                                          \
        BH[ks] = *(const half8*)(_b + ks * 1024);                             \
        BL[ks] = *(const half8*)(_b + 4096 + ks * 1024);                      \
    }                                                                         \
    E2 = lds_e2[(tbase + (T)) * 32 + col];                                    \
} while (0)

#define COMP(T, BH, BL, E2) do {                                              \
    __builtin_amdgcn_s_setprio(1);                                            \
    floatx16 c0 = MFMA(ah[0], BH[0], zeroC);                                  \
    floatx16 c1 = MFMA(ah[0], BL[0], zeroC);                                  \
    c0 = MFMA(ah[1], BH[1], c0);  c1 = MFMA(ah[1], BL[1], c1);                \
    c0 = MFMA(ah[2], BH[2], c0);  c1 = MFMA(ah[2], BL[2], c1);                \
    c0 = MFMA(ah[3], BH[3], c0);  c1 = MFMA(ah[3], BL[3], c1);                \
    c0 = MFMA(al[0], BH[0], c0);  c1 = MFMA(al[2], BH[2], c1);                \
    c0 = MFMA(al[1], BH[1], c0);  c1 = MFMA(al[3], BH[3], c1);                \
    __builtin_amdgcn_s_setprio(0);                                            \
    _Pragma("unroll")                                                         \
    for (int r = 0; r < 16; ++r) {                                            \
        float d = (c0[r] + c1[r]) + (E2);                                     \
        bool c = d < best[r];          /* strict <: earliest tile wins */     \
        best[r] = c ? d          : best[r];                                   \
        bt[r]   = c ? (tbase+(T)) : bt[r];                                    \
    }                                                                         \
} while (0)

// vmcnt(0)+lgkmcnt(0): the waited STAGE was issued a full COMP (~700cy)
// earlier; lgkm guards LDS slot reuse. Raw s_barrier (no __syncthreads).
#define WAITBAR do {                                                          \
    asm volatile("s_waitcnt vmcnt(0) lgkmcnt(0)" ::: "memory");               \
    __builtin_amdgcn_sched_barrier(0);                                        \
    __builtin_amdgcn_s_barrier();                                             \
    __builtin_amdgcn_sched_barrier(0);                                        \
} while (0)

    // Named regsets A/B (rule #20: no runtime-indexed register arrays).
    half8 bhA[4], blA[4], bhB[4], blB[4];
    float e2A, e2B;

    // -------- prologue: e2 + tile 0 staged; tile 1 in flight --------
    gl_lds16(ws_c + WS_E2 + w * 1024 + lane * 16, (char*)lds_e2 + w * 1024);
    STAGE(0, 0);
    WAITBAR;
    READF(0, 0, bhA, blA, e2A);
    STAGE(1, 1);

    // -------- main loop: 16 tiles, READF one ahead of COMP --------
    #pragma unroll 1
    for (int t = 0; t < 16; t += 2) {
        WAITBAR;                               // STAGE(t+1) done; frags(t) done
        READF((t + 1) & 1, t + 1, bhB, blB, e2B);
        if (t + 2 < 16) STAGE((t + 2) & 1, t + 2);
        COMP(t, bhA, blA, e2A);

        WAITBAR;                               // STAGE(t+2) done; frags(t+1) done
        if (t + 2 < 16) READF((t + 2) & 1, t + 2, bhA, blA, e2A);
        if (t + 3 < 16) STAGE((t + 3) & 1, t + 3);
        COMP(t + 1, bhB, blB, e2B);
    }
#undef STAGE
#undef READF
#undef COMP
#undef WAITBAR

    // butterfly argmin across the 32 columns (codes already absolute)
    int code[16];
    #pragma unroll
    for (int r = 0; r < 16; ++r) code[r] = bt[r] * 32 + col;
    #pragma unroll
    for (int m = 1; m < 32; m <<= 1) {
        #pragma unroll
        for (int r = 0; r < 16; ++r) {
            float ov = __shfl_xor(best[r], m, 64);
            int   oc = __shfl_xor(code[r], m, 64);
            bool c = (ov < best[r]) || (ov == best[r] && oc < code[r]);
            best[r] = c ? ov : best[r];
            code[r] = c ? oc : code[r];
        }
    }
    if (col == 0) {    // lanes 0 and 32: 16 rows each
        #pragma unroll
        for (int r = 0; r < 16; ++r) {
            int row = (r & 3) + 8 * (r >> 2) + 4 * sel8;
            sbest[pair][phalf * 32 + row] = best[r];
            scode[pair][phalf * 32 + row] = code[r];
        }
    }
    __syncthreads();

    // combine the two K-halves: strict < (half-0 codes are all smaller)
    if (tid < 64) {
        float d0 = sbest[0][tid], d1 = sbest[1][tid];
        s_final[tid] = (d1 < d0) ? scode[1][tid] : scode[0][tid];
    }
    __syncthreads();

    // indices (coalesced) + quantized gather: 64 pts x 16 float4
    if (tid < 64)
        out[QOUT_ELEMS + (size_t)pgrp * 64 + tid] = (float)s_final[tid];
    float4* outq = (float4*)out;
    const float4* emb4 = (const float4*)emb;
    #pragma unroll
    for (int it = 0; it < 4; ++it) {
        int f  = it * 256 + tid;
        int p  = f >> 4;
        int d4 = f & 15;
        int ks = s_final[p];
        outq[((size_t)pgrp * 64 + p) * (DDIM / 4) + d4] =
            emb4[(size_t)ks * (DDIM / 4) + d4];
    }
}

extern "C" void kernel_launch(void* const* d_in, const int* in_sizes, int n_in,
                              void* d_out, int out_size, void* d_ws, size_t ws_size,
                              hipStream_t stream) {
    const float* z   = (const float*)d_in[0];
    const float* emb = (const float*)d_in[1];
    float* out = (float*)d_out;
    char* ws = (char*)d_ws;

    eprep_kernel<<<KCODES / 4, 256, 0, stream>>>(emb, ws);
    vq_kernel<<<NPTS / 64, 256, 0, stream>>>(z, ws, emb, out);
}

// Round 10
// 107.308 us; speedup vs baseline: 2.2779x; 2.2779x over previous
//
#include <hip/hip_runtime.h>

// Problem: B,H,W,D = 64,32,32,64 ; K=1024 ; N = 65536
#define NPTS   65536
#define DDIM   64
#define KCODES 1024
#define QOUT_ELEMS (NPTS * DDIM)

typedef _Float16 half8    __attribute__((ext_vector_type(8)));
typedef float    floatx16 __attribute__((ext_vector_type(16)));
typedef unsigned int uint;

#define AS1 __attribute__((address_space(1)))
#define AS3 __attribute__((address_space(3)))

// ws: ehp [0,128K) chunk-major f16 | elp [128K,256K) | e2 fp32 [256K,260K)
#define WS_EHP   0
#define WS_ELP   (128*1024)
#define WS_E2    (256*1024)

static __device__ __forceinline__ void gl_lds16(const void* g, void* l) {
    __builtin_amdgcn_global_load_lds((const AS1 uint*)g, (AS3 uint*)l, 16, 0, 0);
}

// ---------------------------------------------------------------------------
// Prep: one wave per code. fp16 hi/lo split, CHUNK-MAJOR tiles:
// tile T=k>>5, chunk j=d>>3, code-in-tile c=k&31:
//   byte off = T*4096 + j*512 + c*16 + (d&7)*2
// e2 (||e||^2) stored as plain fp32 (added post-MFMA, exact).
// ---------------------------------------------------------------------------
__global__ void eprep_kernel(const float* __restrict__ emb, char* __restrict__ ws) {
    const int tid = threadIdx.x;
    const int w = tid >> 6, d = tid & 63;
    const int k = blockIdx.x * 4 + w;
    float v = emb[(size_t)k * DDIM + d];
    _Float16 h = (_Float16)v;
    _Float16 l = (_Float16)(v - (float)h);
    size_t off = (size_t)(k >> 5) * 4096 + (size_t)(d >> 3) * 512
               + (size_t)(k & 31) * 16 + (size_t)(d & 7) * 2;
    *(_Float16*)(ws + WS_EHP + off) = h;
    *(_Float16*)(ws + WS_ELP + off) = l;
    float s = v * v;
    #pragma unroll
    for (int m = 1; m < 64; m <<= 1) s += __shfl_xor(s, m, 64);
    if (d == 0) ((float*)(ws + WS_E2))[k] = s;
}

// ---------------------------------------------------------------------------
// Main: grid 512, block 256 = 4 waves; wave w owns 32 points (pgrp*128+w*32+col)
// over the FULL K=1024 (32 tiles). R6 deep-ring structure byte-for-byte
// (4-deep LDS ring, counted vmcnt never 0 mid-loop, raw s_barrier, READF one
// tile ahead into named regsets) EXCEPT the COMP macro.
//
// Round-10 change (single variable): THREE independent 4-deep MFMA chains
// (was two 6-deep). Register law learned from R8/R9 failures: this kernel
// must run at 2 waves/EU (<=256 unified regs) with <=120 arch VGPR; the
// extra chain costs only +16 AGPR (c2), arch side unchanged.
//   c0 = sum ah[k]*bh[k] ; c1 = sum al[k]*bh[k] ; c2 = sum ah[k]*bl[k]
// (identical 12 products to R6's grouping). Dependent-issue gap = 2 instrs.
// Spill tripwire: WRITE_SIZE > 25MB invalidates the round (R8: 125MB,
// R9: 330MB both spill artifacts, not hypothesis tests).
//
// MFMA 32x32x16 f16 layouts (verified, absmax 0):
//   A[m][k]: m=lane&31, k=(lane>>5)*8+j ; B same with n=lane&31 ;
//   C/D: col=lane&31, row=(r&3)+8*(r>>2)+4*(lane>>5)
// ---------------------------------------------------------------------------
#define MFMA(A,B,C) __builtin_amdgcn_mfma_f32_32x32x16_f16(A,B,C,0,0,0)

__global__ __launch_bounds__(256, 2) void vq_kernel(
    const float* __restrict__ z,
    const char* __restrict__ ws_c,
    const float* __restrict__ emb,
    float* __restrict__ out)
{
    const int tid  = threadIdx.x;
    const int lane = tid & 63;
    const int w    = __builtin_amdgcn_readfirstlane(tid >> 6);
    const int col  = lane & 31;
    const int sel8 = lane >> 5;
    const int pgrp = blockIdx.x;

    __shared__ char  ebuf[4][8192];   // ring: [buf][eh 4KB | el 4KB] = 32KB
    __shared__ float lds_e2[1024];    // 4KB fp32 ||e||^2, all codes
    __shared__ int   s_final[128];

    // ---- A fragments: a = -2 z[pt], hi/lo fp16 ----
    const int pt = pgrp * 128 + w * 32 + col;
    half8 ah[4], al[4];
    {
        const float* zrow = z + (size_t)pt * DDIM + sel8 * 8;
        #pragma unroll
        for (int ks = 0; ks < 4; ++ks) {
            float4 u0 = *(const float4*)(zrow + ks * 16);
            float4 u1 = *(const float4*)(zrow + ks * 16 + 4);
            float tv[8] = {u0.x, u0.y, u0.z, u0.w, u1.x, u1.y, u1.z, u1.w};
            #pragma unroll
            for (int j = 0; j < 8; ++j) {
                float a = -2.0f * tv[j];
                _Float16 hh = (_Float16)a;
                ah[ks][j] = hh;
                al[ks][j] = (_Float16)(a - (float)hh);
            }
        }
    }
    // drain A-frag vmem so loop vmcnt accounting sees ONLY gl_lds ops
    asm volatile("s_waitcnt vmcnt(0)" ::: "memory");
    __builtin_amdgcn_sched_barrier(0);

    const floatx16 zeroC = {};
    float best[16];
    int   bt[16];
    #pragma unroll
    for (int r = 0; r < 16; ++r) { best[r] = 3.4e38f; bt[r] = 0; }

    // wave w stages 2KB/tile: operand = w>>1 (0=eh,1=el), half = w&1
    const int opnd = w >> 1, hsel = w & 1;
    const char* gsrc = ws_c + (opnd ? WS_ELP : WS_EHP) + hsel * 2048 + lane * 16;
    char* lbase = &ebuf[0][0] + opnd * 4096 + hsel * 2048;

#define STAGE(BUF, T) do {                                                    \
    const char* _s = gsrc + (size_t)(T) * 4096;                               \
    char* _d = lbase + (BUF) * 8192;                                          \
    gl_lds16(_s,        _d);                                                  \
    gl_lds16(_s + 1024, _d + 1024);                                           \
} while (0)

    const int myoff = sel8 * 512 + col * 16;   // chunk-major frag base in tile

#define READF(BUF, T, BH, BL, E2) do {                                        \
    const char* _b = &ebuf[BUF][0] + myoff;                                   \
    _Pragma("unroll")                                                         \
    for (int ks = 0; ks < 4; ++ks) {                                          \
        BH[ks] = *(const half8*)(_b + ks * 1024);                             \
        BL[ks] = *(const half8*)(_b + 4096 + ks * 1024);                      \
    }                                                                         \
    E2 = lds_e2[(T) * 32 + col];                                              \
} while (0)

// THREE independent 4-deep chains, round-robin issue (dep gap = 2 instrs).
#define COMP(T, BH, BL, E2) do {                                              \
    __builtin_amdgcn_s_setprio(1);                                            \
    floatx16 c0 = MFMA(ah[0], BH[0], zeroC);                                  \
    floatx16 c1 = MFMA(al[0], BH[0], zeroC);                                  \
    floatx16 c2 = MFMA(ah[0], BL[0], zeroC);                                  \
    c0 = MFMA(ah[1], BH[1], c0);                                              \
    c1 = MFMA(al[1], BH[1], c1);                                              \
    c2 = MFMA(ah[1], BL[1], c2);                                              \
    c0 = MFMA(ah[2], BH[2], c0);                                              \
    c1 = MFMA(al[2], BH[2], c1);                                              \
    c2 = MFMA(ah[2], BL[2], c2);                                              \
    c0 = MFMA(ah[3], BH[3], c0);                                              \
    c1 = MFMA(al[3], BH[3], c1);                                              \
    c2 = MFMA(ah[3], BL[3], c2);                                              \
    __builtin_amdgcn_s_setprio(0);                                            \
    _Pragma("unroll")                                                         \
    for (int r = 0; r < 16; ++r) {                                            \
        float d = (c0[r] + c1[r]) + (c2[r] + (E2));                           \
        bool c = d < best[r];          /* strict <: earliest tile wins */     \
        best[r] = c ? d   : best[r];                                          \
        bt[r]   = c ? (T) : bt[r];                                            \
    }                                                                         \
} while (0)

// counted wait + collective barrier. lgkmcnt(0): my ds_reads (issued a full
// COMP ago) retired before anyone overwrites that ring slot after the barrier.
#define WAITBAR(N) do {                                                       \
    asm volatile("s_waitcnt vmcnt(" #N ") lgkmcnt(0)" ::: "memory");          \
    __builtin_amdgcn_sched_barrier(0);                                        \
    __builtin_amdgcn_s_barrier();                                             \
    __builtin_amdgcn_sched_barrier(0);                                        \
} while (0)

    // Named regsets A/B (rule #20: no runtime-indexed register arrays).
    half8 bhA[4], blA[4], bhB[4], blB[4];
    float e2A, e2B;

    // -------- prologue: e2 + tiles 0..2 in flight (7 ops) --------
    gl_lds16(ws_c + WS_E2 + w * 1024 + lane * 16, (char*)lds_e2 + w * 1024);
    STAGE(0, 0);
    STAGE(1, 1);
    STAGE(2, 2);
    WAITBAR(4);                 // retire e2 + tile0 (3 oldest ops)
    READF(0, 0, bhA, blA, e2A);
    STAGE(3, 3);                // in flight: tiles 1,2,3 = 6 ops

    // -------- main loop: tiles 0..27, always 3 tiles ahead --------
    #pragma unroll 1
    for (int t = 0; t < 28; t += 2) {
        WAITBAR(4);                              // retire tile t+1
        READF((t + 1) & 3, t + 1, bhB, blB, e2B);
        STAGE((t + 4) & 3, t + 4);
        COMP(t, bhA, blA, e2A);

        WAITBAR(4);                              // retire tile t+2
        READF((t + 2) & 3, t + 2, bhA, blA, e2A);
        STAGE((t + 5) & 3, t + 5);
        COMP(t + 1, bhB, blB, e2B);
    }

    // -------- tail: tiles 28..31, draining the ring --------
    WAITBAR(4);                 // in flight {29,30,31}: retire 29
    READF(29 & 3, 29, bhB, blB, e2B);
    COMP(28, bhA, blA, e2A);

    WAITBAR(2);                 // in flight {30,31}: retire 30
    READF(30 & 3, 30, bhA, blA, e2A);
    COMP(29, bhB, blB, e2B);

    WAITBAR(0);                 // in flight {31}: retire 31
    READF(31 & 3, 31, bhB, blB, e2B);
    COMP(30, bhA, blA, e2A);

    COMP(31, bhB, blB, e2B);
#undef STAGE
#undef READF
#undef COMP
#undef WAITBAR

    // materialize codes; butterfly argmin across the 32 columns
    int code[16];
    #pragma unroll
    for (int r = 0; r < 16; ++r) code[r] = bt[r] * 32 + col;
    #pragma unroll
    for (int m = 1; m < 32; m <<= 1) {
        #pragma unroll
        for (int r = 0; r < 16; ++r) {
            float ov = __shfl_xor(best[r], m, 64);
            int   oc = __shfl_xor(code[r], m, 64);
            bool c = (ov < best[r]) || (ov == best[r] && oc < code[r]);
            best[r] = c ? ov : best[r];
            code[r] = c ? oc : code[r];
        }
    }
    if (col == 0) {   // lanes 0 and 32: 16 rows each
        #pragma unroll
        for (int r = 0; r < 16; ++r) {
            int row = (r & 3) + 8 * (r >> 2) + 4 * sel8;
            s_final[w * 32 + row] = code[r];
        }
    }
    __syncthreads();

    // indices (coalesced) + quantized gather: 128 pts x 16 float4
    if (tid < 128)
        out[QOUT_ELEMS + (size_t)pgrp * 128 + tid] = (float)s_final[tid];
    float4* outq = (float4*)out;
    const float4* emb4 = (const float4*)emb;
    #pragma unroll
    for (int it = 0; it < 8; ++it) {
        int f  = it * 256 + tid;
        int p  = f >> 4;
        int d4 = f & 15;
        int ks = s_final[p];
        outq[((size_t)pgrp * 128 + p) * (DDIM / 4) + d4] =
            emb4[(size_t)ks * (DDIM / 4) + d4];
    }
}

extern "C" void kernel_launch(void* const* d_in, const int* in_sizes, int n_in,
                              void* d_out, int out_size, void* d_ws, size_t ws_size,
                              hipStream_t stream) {
    const float* z   = (const float*)d_in[0];
    const float* emb = (const float*)d_in[1];
    float* out = (float*)d_out;
    char* ws = (char*)d_ws;

    eprep_kernel<<<KCODES / 4, 256, 0, stream>>>(emb, ws);
    vq_kernel<<<NPTS / 128, 256, 0, stream>>>(z, ws, emb, out);
}

// Round 11
// 102.628 us; speedup vs baseline: 2.3818x; 1.0456x over previous
//
#include <hip/hip_runtime.h>

// Problem: B,H,W,D = 64,32,32,64 ; K=1024 ; N = 65536
#define NPTS   65536
#define DDIM   64
#define KCODES 1024
#define QOUT_ELEMS (NPTS * DDIM)

typedef _Float16 half8    __attribute__((ext_vector_type(8)));
typedef float    floatx16 __attribute__((ext_vector_type(16)));
typedef unsigned int uint;

#define AS1 __attribute__((address_space(1)))
#define AS3 __attribute__((address_space(3)))

// ws: ehp [0,128K) chunk-major f16 | elp [128K,256K) | e2 fp32 [256K,260K)
#define WS_EHP   0
#define WS_ELP   (128*1024)
#define WS_E2    (256*1024)

static __device__ __forceinline__ void gl_lds16(const void* g, void* l) {
    __builtin_amdgcn_global_load_lds((const AS1 uint*)g, (AS3 uint*)l, 16, 0, 0);
}

// ---------------------------------------------------------------------------
// Prep: one wave per code. fp16 hi/lo split, CHUNK-MAJOR tiles:
// tile T=k>>5, chunk j=d>>3, code-in-tile c=k&31:
//   byte off = T*4096 + j*512 + c*16 + (d&7)*2
// e2 (||e||^2) stored as plain fp32 (added post-MFMA, exact).
// ---------------------------------------------------------------------------
__global__ void eprep_kernel(const float* __restrict__ emb, char* __restrict__ ws) {
    const int tid = threadIdx.x;
    const int w = tid >> 6, d = tid & 63;
    const int k = blockIdx.x * 4 + w;
    float v = emb[(size_t)k * DDIM + d];
    _Float16 h = (_Float16)v;
    _Float16 l = (_Float16)(v - (float)h);
    size_t off = (size_t)(k >> 5) * 4096 + (size_t)(d >> 3) * 512
               + (size_t)(k & 31) * 16 + (size_t)(d & 7) * 2;
    *(_Float16*)(ws + WS_EHP + off) = h;
    *(_Float16*)(ws + WS_ELP + off) = l;
    float s = v * v;
    #pragma unroll
    for (int m = 1; m < 64; m <<= 1) s += __shfl_xor(s, m, 64);
    if (d == 0) ((float*)(ws + WS_E2))[k] = s;
}

// ---------------------------------------------------------------------------
// Main: grid 512, block 256 = 4 waves; wave w owns 32 points (pgrp*128+w*32+col)
// over the FULL K=1024 (32 tiles). R6 deep-ring skeleton (4-deep LDS ring,
// counted vmcnt never 0 mid-loop, raw s_barrier, READF one region ahead).
//
// Round-11 change: DEFERRED ARGMIN. In all prior versions the per-tile argmin
// VALUs (depend on the chain TAIL) sat between chain(t) and chain(t+1),
// serializing ~300cy/tile of VALU issue behind ~780cy of MFMA dep latency
// (measured 1125cy/wave-tile; every pipe <40%). Now region r does:
//   WAITBAR; READF(r+1); STAGE(r+4); CHAIN(r)->acc[r&1]; ARGMIN(r-1) on
//   acc[(r-1)&1]  -- the argmin VALUs are independent of this region's MFMAs
// so they issue inside the chain's dep gaps; chain(r)'s tail latency is
// absorbed by region r+1. Both acc pairs live across boundaries: arch ledger
// accs 64 + best/bt 32 + misc ~16 = 112 < 128 (A-frags + B-regsets can sit
// in AGPRs -- MFMA reads A/B from AGPR on gfx950). e2 save: one mov/region
// (READF(r+1) overwrites the parity slot ARGMIN(r-1) reads).
// Spill tripwire: WRITE_SIZE > 25MB invalidates (R8/R9/R10 all spilled).
// Numerics byte-identical to R6 (same products, same add order) -> absmax 0.
//
// MFMA 32x32x16 f16 layouts (verified, absmax 0):
//   A[m][k]: m=lane&31, k=(lane>>5)*8+j ; B same with n=lane&31 ;
//   C/D: col=lane&31, row=(r&3)+8*(r>>2)+4*(lane>>5)
// ---------------------------------------------------------------------------
#define MFMA(A,B,C) __builtin_amdgcn_mfma_f32_32x32x16_f16(A,B,C,0,0,0)

__global__ __launch_bounds__(256, 2) void vq_kernel(
    const float* __restrict__ z,
    const char* __restrict__ ws_c,
    const float* __restrict__ emb,
    float* __restrict__ out)
{
    const int tid  = threadIdx.x;
    const int lane = tid & 63;
    const int w    = __builtin_amdgcn_readfirstlane(tid >> 6);
    const int col  = lane & 31;
    const int sel8 = lane >> 5;
    const int pgrp = blockIdx.x;

    __shared__ char  ebuf[4][8192];   // ring: [buf][eh 4KB | el 4KB] = 32KB
    __shared__ float lds_e2[1024];    // 4KB fp32 ||e||^2, all codes
    __shared__ int   s_final[128];

    // ---- A fragments: a = -2 z[pt], hi/lo fp16 ----
    const int pt = pgrp * 128 + w * 32 + col;
    half8 ah[4], al[4];
    {
        const float* zrow = z + (size_t)pt * DDIM + sel8 * 8;
        #pragma unroll
        for (int ks = 0; ks < 4; ++ks) {
            float4 u0 = *(const float4*)(zrow + ks * 16);
            float4 u1 = *(const float4*)(zrow + ks * 16 + 4);
            float tv[8] = {u0.x, u0.y, u0.z, u0.w, u1.x, u1.y, u1.z, u1.w};
            #pragma unroll
            for (int j = 0; j < 8; ++j) {
                float a = -2.0f * tv[j];
                _Float16 hh = (_Float16)a;
                ah[ks][j] = hh;
                al[ks][j] = (_Float16)(a - (float)hh);
            }
        }
    }
    // drain A-frag vmem so loop vmcnt accounting sees ONLY gl_lds ops
    asm volatile("s_waitcnt vmcnt(0)" ::: "memory");
    __builtin_amdgcn_sched_barrier(0);

    const floatx16 zeroC = {};
    float best[16];
    int   bt[16];
    #pragma unroll
    for (int r = 0; r < 16; ++r) { best[r] = 3.4e38f; bt[r] = 0; }

    // wave w stages 2KB/tile: operand = w>>1 (0=eh,1=el), half = w&1
    const int opnd = w >> 1, hsel = w & 1;
    const char* gsrc = ws_c + (opnd ? WS_ELP : WS_EHP) + hsel * 2048 + lane * 16;
    char* lbase = &ebuf[0][0] + opnd * 4096 + hsel * 2048;

#define STAGE(BUF, T) do {                                                    \
    const char* _s = gsrc + (size_t)(T) * 4096;                               \
    char* _d = lbase + (BUF) * 8192;                                          \
    gl_lds16(_s,        _d);                                                  \
    gl_lds16(_s + 1024, _d + 1024);                                           \
} while (0)

    const int myoff = sel8 * 512 + col * 16;   // chunk-major frag base in tile

#define READF(BUF, T, BH, BL, E2) do {                                        \
    const char* _b = &ebuf[BUF][0] + myoff;                                   \
    _Pragma("unroll")                                                         \
    for (int ks = 0; ks < 4; ++ks) {                                          \
        BH[ks] = *(const half8*)(_b + ks * 1024);                             \
        BL[ks] = *(const half8*)(_b + 4096 + ks * 1024);                      \
    }                                                                         \
    E2 = lds_e2[(T) * 32 + col];                                              \
} while (0)

// two 6-deep chains into NAMED acc pair (identical products/order to R6)
#define CHAIN(BH, BL, C0, C1) do {                                            \
    __builtin_amdgcn_s_setprio(1);                                            \
    C0 = MFMA(ah[0], BH[0], zeroC);                                           \
    C1 = MFMA(ah[0], BL[0], zeroC);                                           \
    C0 = MFMA(ah[1], BH[1], C0);  C1 = MFMA(ah[1], BL[1], C1);                \
    C0 = MFMA(ah[2], BH[2], C0);  C1 = MFMA(ah[2], BL[2], C1);                \
    C0 = MFMA(ah[3], BH[3], C0);  C1 = MFMA(ah[3], BL[3], C1);                \
    C0 = MFMA(al[0], BH[0], C0);  C1 = MFMA(al[2], BH[2], C1);                \
    C0 = MFMA(al[1], BH[1], C0);  C1 = MFMA(al[3], BH[3], C1);                \
    __builtin_amdgcn_s_setprio(0);                                            \
} while (0)

#define ARGMIN(T, C0, C1, E2) do {                                            \
    _Pragma("unroll")                                                         \
    for (int r = 0; r < 16; ++r) {                                            \
        float d = (C0[r] + C1[r]) + (E2);                                     \
        bool c = d < best[r];          /* strict <: earliest tile wins */     \
        best[r] = c ? d   : best[r];                                          \
        bt[r]   = c ? (T) : bt[r];                                            \
    }                                                                         \
} while (0)

// counted wait + collective barrier. lgkmcnt(0): my ds_reads (issued a full
// region ago) retired before anyone overwrites that ring slot after barrier.
#define WAITBAR(N) do {                                                       \
    asm volatile("s_waitcnt vmcnt(" #N ") lgkmcnt(0)" ::: "memory");          \
    __builtin_amdgcn_sched_barrier(0);                                        \
    __builtin_amdgcn_s_barrier();                                             \
    __builtin_amdgcn_sched_barrier(0);                                        \
} while (0)

    // Named regsets/accs (rule #20: no runtime-indexed register arrays).
    // Parity: even tiles -> A set/accs, odd tiles -> B.
    half8 bhA[4], blA[4], bhB[4], blB[4];
    float e2A, e2B, e2s;
    floatx16 c0A, c1A, c0B, c1B;

    // -------- prologue: e2 + tiles 0..2 in flight (7 ops) --------
    gl_lds16(ws_c + WS_E2 + w * 1024 + lane * 16, (char*)lds_e2 + w * 1024);
    STAGE(0, 0);
    STAGE(1, 1);
    STAGE(2, 2);
    WAITBAR(4);                 // retire e2 + tile0 (3 oldest ops)
    READF(0, 0, bhA, blA, e2A);
    STAGE(3, 3);                // in flight: tiles 1,2,3 = 6 ops

    // -------- region 0: chain(0), no argmin yet --------
    WAITBAR(4);                 // retire tile 1
    READF(1, 1, bhB, blB, e2B);
    STAGE(0, 4);
    CHAIN(bhA, blA, c0A, c1A);

    // -------- main loop: regions 1..26 (pairs), CHAIN(r) + ARGMIN(r-1) -----
    #pragma unroll 1
    for (int t = 1; t < 27; t += 2) {
        // odd region t: chain(t, B), argmin(t-1, accA)
        WAITBAR(4);                              // retire tile t+1
        e2s = e2A;                               // tile t-1's e2 (parity 0)
        READF((t + 1) & 3, t + 1, bhA, blA, e2A);
        STAGE((t + 4) & 3, t + 4);
        CHAIN(bhB, blB, c0B, c1B);
        ARGMIN(t - 1, c0A, c1A, e2s);

        // even region t+1: chain(t+1, A), argmin(t, accB)
        WAITBAR(4);                              // retire tile t+2
        e2s = e2B;                               // tile t's e2 (parity 1)
        READF((t + 2) & 3, t + 2, bhB, blB, e2B);
        STAGE((t + 5) & 3, t + 5);
        CHAIN(bhA, blA, c0A, c1A);
        ARGMIN(t, c0B, c1B, e2s);
    }

    // -------- epilogue regions 27..31 + final argmin --------
    WAITBAR(4);                 // region 27: retire 28; in flight {29,30,31}+stage
    e2s = e2A;
    READF(28 & 3, 28, bhA, blA, e2A);
    STAGE(31 & 3, 31);
    CHAIN(bhB, blB, c0B, c1B);          // tile 27
    ARGMIN(26, c0A, c1A, e2s);

    WAITBAR(4);                 // region 28: retire 29
    e2s = e2B;
    READF(29 & 3, 29, bhB, blB, e2B);
    CHAIN(bhA, blA, c0A, c1A);          // tile 28
    ARGMIN(27, c0B, c1B, e2s);

    WAITBAR(2);                 // region 29: retire 30
    e2s = e2A;
    READF(30 & 3, 30, bhA, blA, e2A);
    CHAIN(bhB, blB, c0B, c1B);          // tile 29
    ARGMIN(28, c0A, c1A, e2s);

    WAITBAR(0);                 // region 30: retire 31
    e2s = e2B;
    READF(31 & 3, 31, bhB, blB, e2B);
    CHAIN(bhA, blA, c0A, c1A);          // tile 30
    ARGMIN(29, c0B, c1B, e2s);

    // region 31: no loads left; compiler inserts lgkm wait for READF(31) regs
    e2s = e2A;
    CHAIN(bhB, blB, c0B, c1B);          // tile 31
    ARGMIN(30, c0A, c1A, e2s);

    ARGMIN(31, c0B, c1B, e2B);
#undef STAGE
#undef READF
#undef CHAIN
#undef ARGMIN
#undef WAITBAR

    // materialize codes; butterfly argmin across the 32 columns
    int code[16];
    #pragma unroll
    for (int r = 0; r < 16; ++r) code[r] = bt[r] * 32 + col;
    #pragma unroll
    for (int m = 1; m < 32; m <<= 1) {
        #pragma unroll
        for (int r = 0; r < 16; ++r) {
            float ov = __shfl_xor(best[r], m, 64);
            int   oc = __shfl_xor(code[r], m, 64);
            bool c = (ov < best[r]) || (ov == best[r] && oc < code[r]);
            best[r] = c ? ov : best[r];
            code[r] = c ? oc : code[r];
        }
    }
    if (col == 0) {   // lanes 0 and 32: 16 rows each
        #pragma unroll
        for (int r = 0; r < 16; ++r) {
            int row = (r & 3) + 8 * (r >> 2) + 4 * sel8;
            s_final[w * 32 + row] = code[r];
        }
    }
    __syncthreads();

    // indices (coalesced) + quantized gather: 128 pts x 16 float4
    if (tid < 128)
        out[QOUT_ELEMS + (size_t)pgrp * 128 + tid] = (float)s_final[tid];
    float4* outq = (float4*)out;
    const float4* emb4 = (const float4*)emb;
    #pragma unroll
    for (int it = 0; it < 8; ++it) {
        int f  = it * 256 + tid;
        int p  = f >> 4;
        int d4 = f & 15;
        int ks = s_final[p];
        outq[((size_t)pgrp * 128 + p) * (DDIM / 4) + d4] =
            emb4[(size_t)ks * (DDIM / 4) + d4];
    }
}

extern "C" void kernel_launch(void* const* d_in, const int* in_sizes, int n_in,
                              void* d_out, int out_size, void* d_ws, size_t ws_size,
                              hipStream_t stream) {
    const float* z   = (const float*)d_in[0];
    const float* emb = (const float*)d_in[1];
    float* out = (float*)d_out;
    char* ws = (char*)d_ws;

    eprep_kernel<<<KCODES / 4, 256, 0, stream>>>(emb, ws);
    vq_kernel<<<NPTS / 128, 256, 0, stream>>>(z, ws, emb, out);
}